// Round 3
// baseline (1717.496 us; speedup 1.0000x reference)
//
#include <hip/hip_runtime.h>
#include <math.h>

#define C 256
#define S 16
#define CR 64
#define NREP 16        // replicated global accumulators (atomic contention /16)
#define UB 8           // rows per batch in k_segsum

// ---------------- Kernel 1: segment sums + counts ----------------
// 128 threads/block; thread t owns channels {2t,2t+1} (float2 = 8 B/lane).
// Accumulate via non-returning ds_add_f32 (fire-and-forget LDS atomics):
// no LDS RMW dependency chain. 8 independent rows' loads in flight per batch.
// Each block owns a CONTIGUOUS row chunk (idx reads sequential, x streaming).
__global__ __launch_bounds__(128) void k_segsum(
    const float* __restrict__ x, const int* __restrict__ idx,
    float* __restrict__ psum, int* __restrict__ pcnt, int nrows)
{
    __shared__ float ls[S][C];
    __shared__ int   lc[S];
    const int t = threadIdx.x;

    for (int i = t; i < S * C; i += 128) (&ls[0][0])[i] = 0.0f;
    if (t < S) lc[t] = 0;
    __syncthreads();

    const int chunk = (nrows + gridDim.x - 1) / gridDim.x;
    const int r0 = blockIdx.x * chunk;
    const int r1 = min(r0 + chunk, nrows);
    const float2* __restrict__ x2 = reinterpret_cast<const float2*>(x);

    int r = r0;
    for (; r + UB <= r1; r += UB) {
        int    sv[UB];
        float2 vv[UB];
        #pragma unroll
        for (int k = 0; k < UB; k++) sv[k] = idx[r + k];          // 1 cache line
        #pragma unroll
        for (int k = 0; k < UB; k++) vv[k] = x2[(r + k) * (C/2) + t]; // 8 KB/block in flight
        #pragma unroll
        for (int k = 0; k < UB; k++) {
            atomicAdd(&ls[sv[k]][2 * t],     vv[k].x);   // ds_add_f32, no return
            atomicAdd(&ls[sv[k]][2 * t + 1], vv[k].y);
            if (t == 0) atomicAdd(&lc[sv[k]], 1);
        }
    }
    for (; r < r1; ++r) {
        const int s = idx[r];
        float2 v = x2[r * (C/2) + t];
        atomicAdd(&ls[s][2 * t],     v.x);
        atomicAdd(&ls[s][2 * t + 1], v.y);
        if (t == 0) atomicAdd(&lc[s], 1);
    }
    __syncthreads();

    const int rep = blockIdx.x & (NREP - 1);
    float* gs = psum + rep * S * C;
    int*   gc = pcnt + rep * S;
    for (int i = t; i < S * C; i += 128) atomicAdd(&gs[i], (&ls[0][0])[i]);
    if (t < S && lc[t]) atomicAdd(&gc[t], lc[t]);
}

// ---------------- Kernel 2: reduce replicas + tiny SE MLP ----------------
__global__ __launch_bounds__(256) void k_mlp(
    const float* __restrict__ psum, const int* __restrict__ pcnt,
    const float* __restrict__ w1, const float* __restrict__ w2,
    float* __restrict__ gate)
{
    __shared__ float sm[S][C];
    __shared__ float h[S][CR];
    __shared__ float cnt[S];
    const int t = threadIdx.x;

    if (t < S) {
        int c = 0;
        #pragma unroll
        for (int r = 0; r < NREP; r++) c += pcnt[r * S + t];
        cnt[t] = fmaxf((float)c, 1.0f);
    }
    __syncthreads();

    for (int i = t; i < S * C; i += 256) {
        float v = 0.0f;
        #pragma unroll
        for (int r = 0; r < NREP; r++) v += psum[r * S * C + i];
        sm[i / C][i % C] = v / cnt[i / C];
    }
    __syncthreads();

    for (int o = t; o < S * CR; o += 256) {
        const int s = o / CR, j = o % CR;
        float acc = 0.0f;
        #pragma unroll 4
        for (int k = 0; k < C; k++) acc += sm[s][k] * w1[k * CR + j];
        h[s][j] = fmaxf(acc, 0.0f);
    }
    __syncthreads();

    for (int o = t; o < S * C; o += 256) {
        const int s = o / C, j = o % C;
        float acc = 0.0f;
        #pragma unroll
        for (int k = 0; k < CR; k++) acc += h[s][k] * w2[k * C + j];
        gate[o] = 1.0f / (1.0f + expf(-acc));
    }
}

// ---------------- Kernel 3: out = x * gate[idx] (R1 version, ~6 TB/s) --------
__global__ __launch_bounds__(256) void k_mod(
    const float* __restrict__ x, const int* __restrict__ idx,
    const float* __restrict__ gate, float* __restrict__ out, int nrows)
{
    const int l    = threadIdx.x & 63;
    const int wrow = threadIdx.x >> 6;
    const float4* __restrict__ x4 = reinterpret_cast<const float4*>(x);
    const float4* __restrict__ g4 = reinterpret_cast<const float4*>(gate);
    float4* __restrict__ o4 = reinterpret_cast<float4*>(out);

    for (int row = blockIdx.x * 4 + wrow; row < nrows; row += gridDim.x * 4) {
        const int s = idx[row];                  // wave-uniform -> broadcast
        float4 v = x4[row * (C / 4) + l];
        const float4 g = g4[s * (C / 4) + l];    // 16 KB table, L1/L2-resident
        v.x *= g.x; v.y *= g.y; v.z *= g.z; v.w *= g.w;
        o4[row * (C / 4) + l] = v;
    }
}

extern "C" void kernel_launch(void* const* d_in, const int* in_sizes, int n_in,
                              void* d_out, int out_size, void* d_ws, size_t ws_size,
                              hipStream_t stream)
{
    const float* x   = (const float*)d_in[0];
    const int*   idx = (const int*)  d_in[1];
    const float* w1  = (const float*)d_in[2];
    const float* w2  = (const float*)d_in[3];
    float* out = (float*)d_out;
    const int nrows = in_sizes[1];

    // ws: [psum: NREP*S*C f32][pcnt: NREP*S i32][gate: S*C f32]
    float* psum = (float*)d_ws;
    int*   pcnt = (int*)(psum + NREP * S * C);
    float* gate = (float*)(pcnt + NREP * S);

    const size_t zero_bytes = NREP * S * C * sizeof(float) + NREP * S * sizeof(int);
    hipMemsetAsync(d_ws, 0, zero_bytes, stream);

    k_segsum<<<2048, 128, 0, stream>>>(x, idx, psum, pcnt, nrows);
    k_mlp<<<1, 256, 0, stream>>>(psum, pcnt, w1, w2, gate);
    k_mod<<<2048, 256, 0, stream>>>(x, idx, gate, out, nrows);
}

// Round 4
// 1154.844 us; speedup vs baseline: 1.4872x; 1.4872x over previous
//
#include <hip/hip_runtime.h>
#include <math.h>

#define C 256
#define S 16
#define CR 64
#define NREP 16        // replicated global accumulators (atomic contention /16)

// ---------------- Kernel 1: segment sums + counts, register-resident ---------
// One wave per 64-row superblock: one coalesced load fetches 64 indices,
// readlane() hands each row's (wave-uniform) segment to a scalar 16-way
// switch over compile-time-indexed float4 register accumulators. Counts via
// ballot/popc once per superblock. No LDS in the hot loop.
__global__ __launch_bounds__(256) void k_segsum(
    const float* __restrict__ x, const int* __restrict__ idx,
    float* __restrict__ psum, int* __restrict__ pcnt, int nrows)
{
    const int lane = threadIdx.x & 63;
    const int wid  = (blockIdx.x * blockDim.x + threadIdx.x) >> 6;
    const int nw   = (gridDim.x * blockDim.x) >> 6;

    float4 a0={0,0,0,0},a1={0,0,0,0},a2={0,0,0,0},a3={0,0,0,0},
           a4={0,0,0,0},a5={0,0,0,0},a6={0,0,0,0},a7={0,0,0,0},
           a8={0,0,0,0},a9={0,0,0,0},a10={0,0,0,0},a11={0,0,0,0},
           a12={0,0,0,0},a13={0,0,0,0},a14={0,0,0,0},a15={0,0,0,0};
    int c0=0,c1=0,c2=0,c3=0,c4=0,c5=0,c6=0,c7=0,
        c8=0,c9=0,c10=0,c11=0,c12=0,c13=0,c14=0,c15=0;

    const float4* __restrict__ x4 = reinterpret_cast<const float4*>(x);
    const int nsb = nrows >> 6;          // 64-row superblocks

    // switch-add: sv is wave-uniform (SGPR) -> scalar branch tree
    #define SCASE(K, V) case K: a##K.x+=V.x; a##K.y+=V.y; a##K.z+=V.z; a##K.w+=V.w; break;
    #define SW(sv, V) switch (sv) { \
        SCASE(0,V)  SCASE(1,V)  SCASE(2,V)  SCASE(3,V) \
        SCASE(4,V)  SCASE(5,V)  SCASE(6,V)  SCASE(7,V) \
        SCASE(8,V)  SCASE(9,V)  SCASE(10,V) SCASE(11,V) \
        SCASE(12,V) SCASE(13,V) SCASE(14,V) SCASE(15,V) }

    for (int sb = wid; sb < nsb; sb += nw) {
        const int row0 = sb << 6;
        const int vidx = idx[row0 + lane];          // 64 indices, 256 B coalesced
        #define CNT(K) c##K += (int)__popcll(__ballot(vidx == K));
        CNT(0)  CNT(1)  CNT(2)  CNT(3)  CNT(4)  CNT(5)  CNT(6)  CNT(7)
        CNT(8)  CNT(9)  CNT(10) CNT(11) CNT(12) CNT(13) CNT(14) CNT(15)
        #undef CNT

        const float4* __restrict__ p = x4 + (size_t)row0 * (C/4) + lane;
        for (int j = 0; j < 64; j += 4) {
            // 4 independent 16 B/lane loads in flight before any consumer
            const float4 v0 = p[(j+0) * (C/4)];
            const float4 v1 = p[(j+1) * (C/4)];
            const float4 v2 = p[(j+2) * (C/4)];
            const float4 v3 = p[(j+3) * (C/4)];
            const int s0 = __builtin_amdgcn_readlane(vidx, j+0);
            const int s1 = __builtin_amdgcn_readlane(vidx, j+1);
            const int s2 = __builtin_amdgcn_readlane(vidx, j+2);
            const int s3 = __builtin_amdgcn_readlane(vidx, j+3);
            SW(s0, v0) SW(s1, v1) SW(s2, v2) SW(s3, v3)
        }
    }

    // tail rows (none when nrows % 64 == 0)
    if (wid == 0) {
        #define TCASE(K, V) case K: a##K.x+=V.x; a##K.y+=V.y; a##K.z+=V.z; a##K.w+=V.w; c##K++; break;
        for (int row = nsb << 6; row < nrows; ++row) {
            const int s = idx[row];
            const float4 v = x4[(size_t)row * (C/4) + lane];
            switch (s) {
                TCASE(0,v)  TCASE(1,v)  TCASE(2,v)  TCASE(3,v)
                TCASE(4,v)  TCASE(5,v)  TCASE(6,v)  TCASE(7,v)
                TCASE(8,v)  TCASE(9,v)  TCASE(10,v) TCASE(11,v)
                TCASE(12,v) TCASE(13,v) TCASE(14,v) TCASE(15,v)
            }
        }
        #undef TCASE
    }
    #undef SW
    #undef SCASE

    // flush into one of NREP replicas
    const int rep = wid & (NREP - 1);
    float* gs = psum + rep * S * C;
    int*   gc = pcnt + rep * S;
    #define FLUSH(K) { float* fp = gs + K * C + 4 * lane; \
        atomicAdd(fp + 0, a##K.x); atomicAdd(fp + 1, a##K.y); \
        atomicAdd(fp + 2, a##K.z); atomicAdd(fp + 3, a##K.w); \
        if (lane == 0 && c##K) atomicAdd(&gc[K], c##K); }
    FLUSH(0)  FLUSH(1)  FLUSH(2)  FLUSH(3)
    FLUSH(4)  FLUSH(5)  FLUSH(6)  FLUSH(7)
    FLUSH(8)  FLUSH(9)  FLUSH(10) FLUSH(11)
    FLUSH(12) FLUSH(13) FLUSH(14) FLUSH(15)
    #undef FLUSH
}

// ---------------- Kernel 2: reduce replicas + tiny SE MLP ----------------
__global__ __launch_bounds__(256) void k_mlp(
    const float* __restrict__ psum, const int* __restrict__ pcnt,
    const float* __restrict__ w1, const float* __restrict__ w2,
    float* __restrict__ gate)
{
    __shared__ float sm[S][C];
    __shared__ float h[S][CR];
    __shared__ float cnt[S];
    const int t = threadIdx.x;

    if (t < S) {
        int c = 0;
        #pragma unroll
        for (int r = 0; r < NREP; r++) c += pcnt[r * S + t];
        cnt[t] = fmaxf((float)c, 1.0f);
    }
    __syncthreads();

    for (int i = t; i < S * C; i += 256) {
        float v = 0.0f;
        #pragma unroll
        for (int r = 0; r < NREP; r++) v += psum[r * S * C + i];
        sm[i / C][i % C] = v / cnt[i / C];
    }
    __syncthreads();

    for (int o = t; o < S * CR; o += 256) {
        const int s = o / CR, j = o % CR;
        float acc = 0.0f;
        #pragma unroll 4
        for (int k = 0; k < C; k++) acc += sm[s][k] * w1[k * CR + j];
        h[s][j] = fmaxf(acc, 0.0f);
    }
    __syncthreads();

    for (int o = t; o < S * C; o += 256) {
        const int s = o / C, j = o % C;
        float acc = 0.0f;
        #pragma unroll
        for (int k = 0; k < CR; k++) acc += h[s][k] * w2[k * C + j];
        gate[o] = 1.0f / (1.0f + expf(-acc));
    }
}

// ---------------- Kernel 3: out = x * gate[idx] (exact R1 version) -----------
__global__ __launch_bounds__(256) void k_mod(
    const float* __restrict__ x, const int* __restrict__ idx,
    const float* __restrict__ gate, float* __restrict__ out, int nrows)
{
    const int l    = threadIdx.x & 63;
    const int wrow = threadIdx.x >> 6;
    const float4* __restrict__ x4 = reinterpret_cast<const float4*>(x);
    const float4* __restrict__ g4 = reinterpret_cast<const float4*>(gate);
    float4* __restrict__ o4 = reinterpret_cast<float4*>(out);

    for (int row = blockIdx.x * 4 + wrow; row < nrows; row += gridDim.x * 4) {
        const int s = idx[row];                  // wave-uniform -> broadcast
        float4 v = x4[row * (C / 4) + l];
        const float4 g = g4[s * (C / 4) + l];    // 16 KB table, L1/L2-resident
        v.x *= g.x; v.y *= g.y; v.z *= g.z; v.w *= g.w;
        o4[row * (C / 4) + l] = v;
    }
}

extern "C" void kernel_launch(void* const* d_in, const int* in_sizes, int n_in,
                              void* d_out, int out_size, void* d_ws, size_t ws_size,
                              hipStream_t stream)
{
    const float* x   = (const float*)d_in[0];
    const int*   idx = (const int*)  d_in[1];
    const float* w1  = (const float*)d_in[2];
    const float* w2  = (const float*)d_in[3];
    float* out = (float*)d_out;
    const int nrows = in_sizes[1];

    // ws: [psum: NREP*S*C f32][pcnt: NREP*S i32][gate: S*C f32]
    float* psum = (float*)d_ws;
    int*   pcnt = (int*)(psum + NREP * S * C);
    float* gate = (float*)(pcnt + NREP * S);

    const size_t zero_bytes = NREP * S * C * sizeof(float) + NREP * S * sizeof(int);
    hipMemsetAsync(d_ws, 0, zero_bytes, stream);

    k_segsum<<<2048, 256, 0, stream>>>(x, idx, psum, pcnt, nrows);
    k_mlp<<<1, 256, 0, stream>>>(psum, pcnt, w1, w2, gate);
    k_mod<<<2048, 256, 0, stream>>>(x, idx, gate, out, nrows);
}

// Round 5
// 740.198 us; speedup vs baseline: 2.3203x; 1.5602x over previous
//
#include <hip/hip_runtime.h>
#include <math.h>

#define C 256
#define S 16
#define CR 64
#define NREP 16        // psum replicas (atomic contention /16)

// ---------------- Kernel 0: histogram of idx (counts per segment) ------------
__global__ __launch_bounds__(256) void k_hist(
    const int* __restrict__ idx, int* __restrict__ pcnt, int nrows)
{
    const int lane = threadIdx.x & 63;
    const int tid  = blockIdx.x * blockDim.x + threadIdx.x;
    const int T    = gridDim.x * blockDim.x;
    const int padded = ((nrows + 63) >> 6) << 6;   // wave-uniform trip count

    int c0=0,c1=0,c2=0,c3=0,c4=0,c5=0,c6=0,c7=0,
        c8=0,c9=0,c10=0,c11=0,c12=0,c13=0,c14=0,c15=0;

    for (int i = tid; i < padded; i += T) {
        const int v = (i < nrows) ? idx[i] : -1;
        #define CNT(K) c##K += (int)__popcll(__ballot(v == K));
        CNT(0)  CNT(1)  CNT(2)  CNT(3)  CNT(4)  CNT(5)  CNT(6)  CNT(7)
        CNT(8)  CNT(9)  CNT(10) CNT(11) CNT(12) CNT(13) CNT(14) CNT(15)
        #undef CNT
    }
    if (lane == 0) {
        #define FL(K) if (c##K) atomicAdd(&pcnt[K], c##K);
        FL(0)  FL(1)  FL(2)  FL(3)  FL(4)  FL(5)  FL(6)  FL(7)
        FL(8)  FL(9)  FL(10) FL(11) FL(12) FL(13) FL(14) FL(15)
        #undef FL
    }
}

// ---------------- Kernel 1: segment sums, branch-free predicated FMAC --------
// One wave per 4-row batch; lane l owns channels 4l..4l+3 (float4, 16 B/lane).
// Accumulator select is ARITHMETIC: m = (s==K)?1:0 ; aK = fma(m, v, aK).
// Straight-line body -> compiler pipelines loads; no LDS / branches in loop.
__global__ __launch_bounds__(256, 2) void k_segsum(
    const float* __restrict__ x, const int* __restrict__ idx,
    float* __restrict__ psum, int nrows)
{
    const int lane = threadIdx.x & 63;
    const int w    = threadIdx.x >> 6;                 // wave in block: 0..3
    const int gw   = blockIdx.x * 4 + w;               // global wave id
    const int nw   = gridDim.x * 4;

    float4 a0={0,0,0,0},a1={0,0,0,0},a2={0,0,0,0},a3={0,0,0,0},
           a4={0,0,0,0},a5={0,0,0,0},a6={0,0,0,0},a7={0,0,0,0},
           a8={0,0,0,0},a9={0,0,0,0},a10={0,0,0,0},a11={0,0,0,0},
           a12={0,0,0,0},a13={0,0,0,0},a14={0,0,0,0},a15={0,0,0,0};

    const float4* __restrict__ x4 = reinterpret_cast<const float4*>(x);

    #define ACC1(K, sv, vv) { const float m = (sv == K) ? 1.0f : 0.0f; \
        a##K.x = fmaf(m, vv.x, a##K.x); a##K.y = fmaf(m, vv.y, a##K.y); \
        a##K.z = fmaf(m, vv.z, a##K.z); a##K.w = fmaf(m, vv.w, a##K.w); }
    #define ROW(sv, vv) \
        ACC1(0,sv,vv)  ACC1(1,sv,vv)  ACC1(2,sv,vv)  ACC1(3,sv,vv) \
        ACC1(4,sv,vv)  ACC1(5,sv,vv)  ACC1(6,sv,vv)  ACC1(7,sv,vv) \
        ACC1(8,sv,vv)  ACC1(9,sv,vv)  ACC1(10,sv,vv) ACC1(11,sv,vv) \
        ACC1(12,sv,vv) ACC1(13,sv,vv) ACC1(14,sv,vv) ACC1(15,sv,vv)

    const int nbatch = nrows >> 2;                     // 4-row batches
    for (int b = gw; b < nbatch; b += nw) {
        const int r = b << 2;
        const int s0 = __builtin_amdgcn_readfirstlane(idx[r + 0]);
        const int s1 = __builtin_amdgcn_readfirstlane(idx[r + 1]);
        const int s2 = __builtin_amdgcn_readfirstlane(idx[r + 2]);
        const int s3 = __builtin_amdgcn_readfirstlane(idx[r + 3]);
        const float4* __restrict__ p = x4 + (size_t)r * (C/4) + lane;
        const float4 v0 = p[0 * (C/4)];    // imm offsets 0,1024,2048,3072 B
        const float4 v1 = p[1 * (C/4)];
        const float4 v2 = p[2 * (C/4)];
        const float4 v3 = p[3 * (C/4)];
        ROW(s0, v0) ROW(s1, v1) ROW(s2, v2) ROW(s3, v3)
    }
    if (gw == 0) {                                     // tail rows (none if %4==0)
        for (int r = nbatch << 2; r < nrows; ++r) {
            const int s = __builtin_amdgcn_readfirstlane(idx[r]);
            const float4 v = x4[(size_t)r * (C/4) + lane];
            ROW(s, v)
        }
    }
    #undef ROW
    #undef ACC1

    // block-level LDS reduction, then one atomic per element per block
    __shared__ float red[4][S][C];                     // 64 KB
    #define ST(K) *reinterpret_cast<float4*>(&red[w][K][4 * lane]) = a##K;
    ST(0)  ST(1)  ST(2)  ST(3)  ST(4)  ST(5)  ST(6)  ST(7)
    ST(8)  ST(9)  ST(10) ST(11) ST(12) ST(13) ST(14) ST(15)
    #undef ST
    __syncthreads();

    const int t   = threadIdx.x;                       // 0..255 = channel
    const int rep = blockIdx.x & (NREP - 1);
    float* gs = psum + (size_t)rep * S * C;
    #pragma unroll
    for (int s_ = 0; s_ < S; s_++) {
        const float v = red[0][s_][t] + red[1][s_][t] +
                        red[2][s_][t] + red[3][s_][t];
        atomicAdd(&gs[s_ * C + t], v);
    }
}

// ---------------- Kernel 2: reduce replicas + tiny SE MLP ----------------
__global__ __launch_bounds__(256) void k_mlp(
    const float* __restrict__ psum, const int* __restrict__ pcnt,
    const float* __restrict__ w1, const float* __restrict__ w2,
    float* __restrict__ gate)
{
    __shared__ float sm[S][C];
    __shared__ float h[S][CR];
    __shared__ float cnt[S];
    const int t = threadIdx.x;

    if (t < S) cnt[t] = fmaxf((float)pcnt[t], 1.0f);
    __syncthreads();

    for (int i = t; i < S * C; i += 256) {
        float v = 0.0f;
        #pragma unroll
        for (int r = 0; r < NREP; r++) v += psum[r * S * C + i];
        sm[i / C][i % C] = v / cnt[i / C];
    }
    __syncthreads();

    for (int o = t; o < S * CR; o += 256) {
        const int s = o / CR, j = o % CR;
        float acc = 0.0f;
        #pragma unroll 4
        for (int k = 0; k < C; k++) acc += sm[s][k] * w1[k * CR + j];
        h[s][j] = fmaxf(acc, 0.0f);
    }
    __syncthreads();

    for (int o = t; o < S * C; o += 256) {
        const int s = o / C, j = o % C;
        float acc = 0.0f;
        #pragma unroll
        for (int k = 0; k < CR; k++) acc += h[s][k] * w2[k * C + j];
        gate[o] = 1.0f / (1.0f + expf(-acc));
    }
}

// ---------------- Kernel 3: out = x * gate[idx] (exact R1 version) -----------
__global__ __launch_bounds__(256) void k_mod(
    const float* __restrict__ x, const int* __restrict__ idx,
    const float* __restrict__ gate, float* __restrict__ out, int nrows)
{
    const int l    = threadIdx.x & 63;
    const int wrow = threadIdx.x >> 6;
    const float4* __restrict__ x4 = reinterpret_cast<const float4*>(x);
    const float4* __restrict__ g4 = reinterpret_cast<const float4*>(gate);
    float4* __restrict__ o4 = reinterpret_cast<float4*>(out);

    for (int row = blockIdx.x * 4 + wrow; row < nrows; row += gridDim.x * 4) {
        const int s = idx[row];                  // wave-uniform -> broadcast
        float4 v = x4[row * (C / 4) + l];
        const float4 g = g4[s * (C / 4) + l];    // 16 KB table, L1/L2-resident
        v.x *= g.x; v.y *= g.y; v.z *= g.z; v.w *= g.w;
        o4[row * (C / 4) + l] = v;
    }
}

extern "C" void kernel_launch(void* const* d_in, const int* in_sizes, int n_in,
                              void* d_out, int out_size, void* d_ws, size_t ws_size,
                              hipStream_t stream)
{
    const float* x   = (const float*)d_in[0];
    const int*   idx = (const int*)  d_in[1];
    const float* w1  = (const float*)d_in[2];
    const float* w2  = (const float*)d_in[3];
    float* out = (float*)d_out;
    const int nrows = in_sizes[1];

    // ws: [psum: NREP*S*C f32][pcnt: S i32][gate: S*C f32]
    float* psum = (float*)d_ws;
    int*   pcnt = (int*)(psum + NREP * S * C);
    float* gate = (float*)(pcnt + S);

    const size_t zero_bytes = NREP * S * C * sizeof(float) + S * sizeof(int);
    hipMemsetAsync(d_ws, 0, zero_bytes, stream);

    k_hist  <<<  64, 256, 0, stream>>>(idx, pcnt, nrows);
    k_segsum<<<1024, 256, 0, stream>>>(x, idx, psum, nrows);
    k_mlp   <<<   1, 256, 0, stream>>>(psum, pcnt, w1, w2, gate);
    k_mod   <<<2048, 256, 0, stream>>>(x, idx, gate, out, nrows);
}